// Round 7
// baseline (881.895 us; speedup 1.0000x reference)
//
#include <hip/hip_runtime.h>
#include <hip/hip_bf16.h>
#include <math.h>

// Problem constants
#define BB 4
#define VV 8192
#define EE 256
#define HH 8
#define KK 6
#define NP (BB*VV)          // 32768 points total

// ---------------- workspace layout (bytes), total ~86.7 MB ----------------
#define OFF_XV4  0            // float4[NP]            524288
#define OFF_KNN  524288       // int[NP*6]             786432
#define OFF_XWS  1310720      // float[NP]             131072
#define OFF_XWC  1441792      // float[NP]             131072
#define OFF_XB   1572864      // bf16[NP*256]          16777216
#define OFF_WB   18350080     // bf16[1024*256]        524288
#define OFF_QKV  18874368     // bf16[NP*768]          50331648
#define OFF_AO   69206016     // bf16[NP*256]          16777216
#define OFF_SXV  85983232     // float4[NP] sorted     524288
#define OFF_SPM  86507520     // int[NP] perm          131072  -> ends 86638592

typedef float f32x4 __attribute__((ext_vector_type(4)));
typedef __bf16 bf16x8 __attribute__((ext_vector_type(8)));

__device__ __forceinline__ unsigned short f2b(float f) {
  __hip_bfloat16 h = __float2bfloat16(f);
  return *reinterpret_cast<unsigned short*>(&h);
}
__device__ __forceinline__ float b2f(unsigned short u) {
  unsigned v = ((unsigned)u) << 16;
  return __uint_as_float(v);
}

// monotone float -> uint map (total order, matches float order incl. negatives)
__device__ __forceinline__ unsigned sortable(float f) {
  unsigned u = __float_as_uint(f);
  return u ^ ((unsigned)((int)u >> 31) | 0x80000000u);
}
__device__ __forceinline__ unsigned long long pack_key(float dist, int j) {
  return ((unsigned long long)sortable(dist) << 32) | (unsigned)j;
}
__device__ __forceinline__ float unpack_dist(unsigned long long k) {
  unsigned du = (unsigned)(k >> 32);
  du = (du & 0x80000000u) ? (du ^ 0x80000000u) : ~du;
  return __uint_as_float(du);
}

// ---------------- prep: pack xyz+sq, zero scatter accumulators ----------------
__global__ void prep_kernel(const float* __restrict__ xv, float4* __restrict__ xv4,
                            float* __restrict__ xw_sum, float* __restrict__ xw_cnt) {
  int i = blockIdx.x * blockDim.x + threadIdx.x;
  if (i >= NP) return;
  float x0 = xv[i*3+0], x1 = xv[i*3+1], x2 = xv[i*3+2];
  // exact fp32 op order of the reference: ((x0*x0 + x1*x1) + x2*x2), no FMA contraction
  float sq = __fadd_rn(__fadd_rn(__fmul_rn(x0,x0), __fmul_rn(x1,x1)), __fmul_rn(x2,x2));
  xv4[i] = make_float4(x0, x1, x2, sq);
  xw_sum[i] = 0.f;
  xw_cnt[i] = 0.f;
}

// ---------------- f32 -> bf16 bulk convert (RNE) ----------------
__global__ void cvt_bf16(const float* __restrict__ src, unsigned short* __restrict__ dst, int n4) {
  int i = blockIdx.x * blockDim.x + threadIdx.x;
  if (i >= n4) return;
  float4 v = ((const float4*)src)[i];
  ushort4 o;
  o.x = f2b(v.x); o.y = f2b(v.y); o.z = f2b(v.z); o.w = f2b(v.w);
  ((ushort4*)dst)[i] = o;
}

// ---------------- per-batch bitonic sort by x (u64 keys in LDS) ----------------
// One block per batch, 1024 threads. key = sortable(x)<<32 | local_idx.
__global__ __launch_bounds__(1024) void sort_kernel(const float4* __restrict__ xv4,
                                                    float4* __restrict__ sxv4,
                                                    int* __restrict__ sperm) {
  __shared__ unsigned long long keys[VV];   // 64 KB
  int tid = threadIdx.x;
  int bb = blockIdx.x * VV;
#pragma unroll
  for (int t = 0; t < 8; ++t) {
    int i = tid + t*1024;
    keys[i] = ((unsigned long long)sortable(xv4[bb + i].x) << 32) | (unsigned)i;
  }
  for (int k = 2; k <= VV; k <<= 1) {
    for (int jj = k >> 1; jj > 0; jj >>= 1) {
      __syncthreads();
#pragma unroll
      for (int t = 0; t < 4; ++t) {
        int c = tid + t*1024;                           // comparator 0..4095
        int i = ((c & ~(jj-1)) << 1) | (c & (jj-1));
        int p = i + jj;
        bool up = ((i & k) == 0);
        unsigned long long a = keys[i], b = keys[p];
        if ((a > b) == up) { keys[i] = b; keys[p] = a; }
      }
    }
  }
  __syncthreads();
#pragma unroll
  for (int t = 0; t < 8; ++t) {
    int r = tid + t*1024;
    int idx = (int)(unsigned)keys[r];    // batch-LOCAL original index
    sxv4[bb + r] = xv4[bb + idx];
    sperm[bb + r] = idx;
  }
}

// ---------------- KNN via sorted-x window scan ----------------
// Block = 256 threads = 4 waves; 64 queries/block (one per lane), each wave
// owns one of 4 interleaved streams: {left,right} x {even,odd} stride-2.
// Stream stops when (dx)^2 > d5 + MARGIN (conservative: computed dist >=
// true dist - ~1e-5 >= dx^2 - 1e-5). Distances use the reference's exact
// fp32 op order; top-6 kept as packed (sortable dist, batch-local idx) u64 —
// order-independent exact tie-break. Streams merged in LDS.
#define MARGIN 1e-3f

#define INSU(key) \
  if (key < k5) { \
    bool b4 = key < k4, b3 = key < k3, b2 = key < k2, b1 = key < k1, b0 = key < k0; \
    k5 = b4 ? k4 : key; \
    k4 = b4 ? (b3 ? k3 : key) : k4; \
    k3 = b3 ? (b2 ? k2 : key) : k3; \
    k2 = b2 ? (b1 ? k1 : key) : k2; \
    k1 = b1 ? (b0 ? k0 : key) : k1; \
    k0 = b0 ? key : k0; \
  }

__global__ __launch_bounds__(256) void knn_scan(const float4* __restrict__ sxv4,
                                                const int* __restrict__ sperm,
                                                int* __restrict__ knn_idx) {
  __shared__ unsigned long long sk[64][25];   // 4 sides x 6 keys (+pad)
  int lane = threadIdx.x & 63;
  int side = threadIdx.x >> 6;                // 0:left-odd 1:left-even 2:self+right-even 3:right-odd
  int g = blockIdx.x * 64 + lane;             // global sorted position
  int bb = (g >> 13) << 13;                   // batch base

  float4 me = sxv4[g];
  float mx = me.x, my = me.y, mz = me.z, sqq = me.w;
  int myidx = sperm[g];                       // batch-LOCAL original index

  unsigned long long k0=~0ull,k1=~0ull,k2=~0ull,k3=~0ull,k4=~0ull,k5=~0ull;
  float d5f = __uint_as_float(0x7f7fffffu);   // FLT_MAX until chain is full

  int step = (side & 2) ? 2 : -2;
  int p0 = (side == 0) ? g - 1 : (side == 1) ? g - 2 : (side == 2) ? g : g + 1;

  for (int p = p0; (unsigned)(p - bb) < (unsigned)VV; p += step) {
    float4 c = sxv4[p];
    float dx = mx - c.x;
    if (dx * dx > d5f + MARGIN) break;
    // reference fp32 semantics: d = (sq_v + sq_w) - 2*dot
    float dot  = __fadd_rn(__fadd_rn(__fmul_rn(mx,c.x), __fmul_rn(my,c.y)), __fmul_rn(mz,c.z));
    float dist = __fsub_rn(__fadd_rn(sqq, c.w), __fmul_rn(2.0f, dot));
    unsigned long long key = pack_key(dist, sperm[p]);
    if (key < k5) {
      bool b4 = key < k4, b3 = key < k3, b2 = key < k2, b1 = key < k1, b0 = key < k0;
      k5 = b4 ? k4 : key;
      k4 = b4 ? (b3 ? k3 : key) : k4;
      k3 = b3 ? (b2 ? k2 : key) : k3;
      k2 = b2 ? (b1 ? k1 : key) : k2;
      k1 = b1 ? (b0 ? k0 : key) : k1;
      k0 = b0 ? key : k0;
      if (k5 != ~0ull) d5f = unpack_dist(k5);
    }
  }

  sk[lane][side*6+0]=k0; sk[lane][side*6+1]=k1; sk[lane][side*6+2]=k2;
  sk[lane][side*6+3]=k3; sk[lane][side*6+4]=k4; sk[lane][side*6+5]=k5;
  __syncthreads();
  if (side == 0) {
#pragma unroll
    for (int s = 6; s < 24; ++s) {
      unsigned long long key = sk[lane][s];
      INSU(key);
    }
    int grow = bb + myidx;    // GLOBAL point id (bug fix: was myidx alone)
    knn_idx[grow*6+0] = (int)(unsigned)k0;
    knn_idx[grow*6+1] = (int)(unsigned)k1;
    knn_idx[grow*6+2] = (int)(unsigned)k2;
    knn_idx[grow*6+3] = (int)(unsigned)k3;
    knn_idx[grow*6+4] = (int)(unsigned)k4;
    knn_idx[grow*6+5] = (int)(unsigned)k5;
  }
}

// ---------------- bf16 MFMA GEMM: C[m,n] = sum_k A[m,k]*B[n,k], K=256 ----------------
template<bool OUT_BF16>
__global__ __launch_bounds__(256) void gemm_bf16(const unsigned short* __restrict__ A,
                                                 const unsigned short* __restrict__ Bw,
                                                 void* __restrict__ Cv,
                                                 const float* __restrict__ R,
                                                 int ldc) {
  __shared__ unsigned short ABs[8192];   // A tile [0,4096), B tile [4096,8192) ushort units
  int tid = threadIdx.x;
  int lane = tid & 63;
  int w = tid >> 6;
  int bm = blockIdx.x * 128;
  int bn = blockIdx.y * 128;
  int wr = w >> 1, wc = w & 1;

  f32x4 acc[4][4] = {};

  for (int ks = 0; ks < 8; ++ks) {
    int k0 = ks * 32;
    __syncthreads();
#pragma unroll
    for (int t = 0; t < 4; ++t) {
      int bg = (t*4 + w) * 64;           // wave-uniform granule base
      int g = bg + lane;
      const unsigned short* src;
      if (bg < 512) {                    // A granules
        int r = g >> 2, kb = g & 3;
        src = A + (size_t)(bm + r) * 256 + k0 + kb*8;
      } else {                           // B granules
        int g2 = g - 512;
        int r = g2 >> 2, kb = g2 & 3;
        src = Bw + (size_t)(bn + r) * 256 + k0 + kb*8;
      }
      __builtin_amdgcn_global_load_lds(
        (const __attribute__((address_space(1))) unsigned int*)src,
        (__attribute__((address_space(3))) unsigned int*)&ABs[bg*8],
        16, 0, 0);
    }
    __syncthreads();

    bf16x8 af[4], bfr[4];
#pragma unroll
    for (int m = 0; m < 4; ++m)
      af[m] = *(const bf16x8*)&ABs[(wr*64 + m*16 + (lane&15))*32 + (lane>>4)*8];
#pragma unroll
    for (int n = 0; n < 4; ++n)
      bfr[n] = *(const bf16x8*)&ABs[4096 + (wc*64 + n*16 + (lane&15))*32 + (lane>>4)*8];
#pragma unroll
    for (int m = 0; m < 4; ++m)
#pragma unroll
      for (int n = 0; n < 4; ++n)
        acc[m][n] = __builtin_amdgcn_mfma_f32_16x16x32_bf16(af[m], bfr[n], acc[m][n], 0, 0, 0);
  }

  int rb = bm + wr*64 + (lane>>4)*4;
  int cb = bn + wc*64 + (lane&15);
#pragma unroll
  for (int m = 0; m < 4; ++m)
#pragma unroll
    for (int n = 0; n < 4; ++n)
#pragma unroll
      for (int i = 0; i < 4; ++i) {
        int row = rb + m*16 + i;
        int col = cb + n*16;
        float v = acc[m][n][i];
        if (OUT_BF16) {
          ((unsigned short*)Cv)[(size_t)row*ldc + col] = f2b(v);
        } else {
          ((float*)Cv)[(size_t)row*ldc + col] = v + R[(size_t)row*ldc + col];
        }
      }
}

// ---------------- per-point attention: one wave per point (bf16 QKV) ----------------
__global__ __launch_bounds__(256) void attn_kernel(const unsigned short* __restrict__ QKV,
                                                   const int* __restrict__ knn_idx,
                                                   unsigned short* __restrict__ attn_out,
                                                   float* __restrict__ xw_sum,
                                                   float* __restrict__ xw_cnt) {
  int p = blockIdx.x * 4 + (threadIdx.x >> 6);   // point id
  int lane = threadIdx.x & 63;
  size_t gbase = (size_t)(p >> 13) << 13;        // batch base
  size_t prow = (size_t)p * 768;

  ushort4 qv = *(const ushort4*)&QKV[prow + lane*4];
  ushort4 sv = *(const ushort4*)&QKV[prow + 512 + lane*4];
  float qx=b2f(qv.x), qy=b2f(qv.y), qz=b2f(qv.z), qw=b2f(qv.w);
  float sx=b2f(sv.x), sy=b2f(sv.y), sz=b2f(sv.z), sw=b2f(sv.w);

  int idx[KK];
#pragma unroll
  for (int j = 0; j < KK; ++j) idx[j] = knn_idx[p*KK + j];

  float s[KK];
  float vx[KK], vy[KK], vz[KK], vw[KK];
#pragma unroll
  for (int j = 0; j < KK; ++j) {
    size_t r = (gbase + idx[j]) * 768;
    ushort4 kv = *(const ushort4*)&QKV[r + 256 + lane*4];
    ushort4 vv = *(const ushort4*)&QKV[r + 512 + lane*4];
    float t = qx*b2f(kv.x) + qy*b2f(kv.y) + qz*b2f(kv.z) + qw*b2f(kv.w);
    t += __shfl_xor(t, 1);
    t += __shfl_xor(t, 2);
    t += __shfl_xor(t, 4);
    s[j] = t * 0.17677669529663687f;   // 1/sqrt(32)
    vx[j] = b2f(vv.x); vy[j] = b2f(vv.y); vz[j] = b2f(vv.z); vw[j] = b2f(vv.w);
  }

  float m = s[0];
#pragma unroll
  for (int j = 1; j < KK; ++j) m = fmaxf(m, s[j]);
  float e[KK], denom = 0.f;
#pragma unroll
  for (int j = 0; j < KK; ++j) { e[j] = expf(s[j] - m); denom += e[j]; }
  float inv = 1.0f / denom;
#pragma unroll
  for (int j = 0; j < KK; ++j) e[j] *= inv;

  float ox=0.f, oy=0.f, oz=0.f, ow=0.f;
#pragma unroll
  for (int j = 0; j < KK; ++j) {
    float a = e[j];
    ox += a * (vx[j] - sx);
    oy += a * (vy[j] - sy);
    oz += a * (vz[j] - sz);
    ow += a * (vw[j] - sw);
  }
  ushort4 ov;
  ov.x = f2b(ox); ov.y = f2b(oy); ov.z = f2b(oz); ov.w = f2b(ow);
  *(ushort4*)&attn_out[(size_t)p * 256 + lane*4] = ov;

  // x_w scatter: mean over heads (orbit of xor{8,16,32} = one lane per head)
#pragma unroll
  for (int j = 0; j < KK; ++j) {
    float t = e[j];
    t += __shfl_xor(t, 8);
    t += __shfl_xor(t, 16);
    t += __shfl_xor(t, 32);
    if (lane == 0) {
      atomicAdd(&xw_sum[gbase + idx[j]], t * 0.125f);
      atomicAdd(&xw_cnt[gbase + idx[j]], 1.0f);
    }
  }
}

// ---------------- finalize: xw_out = sum/(count+1) ----------------
__global__ void finalize_xw(const float* __restrict__ xw_sum,
                            const float* __restrict__ xw_cnt,
                            float* __restrict__ out) {
  int i = blockIdx.x * blockDim.x + threadIdx.x;
  if (i < NP) out[i] = xw_sum[i] / (xw_cnt[i] + 1.0f);
}

extern "C" void kernel_launch(void* const* d_in, const int* in_sizes, int n_in,
                              void* d_out, int out_size, void* d_ws, size_t ws_size,
                              hipStream_t stream) {
  const float* x     = (const float*)d_in[0];   // [B,V,E]
  const float* xv    = (const float*)d_in[1];   // [B,V,3]
  const float* w_in  = (const float*)d_in[2];   // [3E,E]
  const float* w_out = (const float*)d_in[3];   // [E,E]
  float* out = (float*)d_out;

  char* ws = (char*)d_ws;
  float4*         xv4    = (float4*)(ws + OFF_XV4);
  int*            knn    = (int*)(ws + OFF_KNN);
  float*          xw_sum = (float*)(ws + OFF_XWS);
  float*          xw_cnt = (float*)(ws + OFF_XWC);
  unsigned short* xb     = (unsigned short*)(ws + OFF_XB);
  unsigned short* wb     = (unsigned short*)(ws + OFF_WB);
  unsigned short* qkv    = (unsigned short*)(ws + OFF_QKV);
  unsigned short* ao     = (unsigned short*)(ws + OFF_AO);
  float4*         sxv4   = (float4*)(ws + OFF_SXV);
  int*            sperm  = (int*)(ws + OFF_SPM);

  prep_kernel<<<(NP + 255) / 256, 256, 0, stream>>>(xv, xv4, xw_sum, xw_cnt);
  cvt_bf16<<<(NP*256/4 + 255)/256, 256, 0, stream>>>(x, xb, NP*256/4);
  cvt_bf16<<<(768*256/4 + 255)/256, 256, 0, stream>>>(w_in, wb, 768*256/4);
  cvt_bf16<<<(256*256/4 + 255)/256, 256, 0, stream>>>(w_out, wb + 768*256, 256*256/4);

  sort_kernel<<<BB, 1024, 0, stream>>>(xv4, sxv4, sperm);
  knn_scan<<<NP/64, 256, 0, stream>>>(sxv4, sperm, knn);

  // QKV = x @ in_proj_w.T   [32768,768] bf16
  gemm_bf16<true><<<dim3(NP/128, 768/128), 256, 0, stream>>>(xb, wb, qkv, nullptr, 768);

  attn_kernel<<<NP / 4, 256, 0, stream>>>(qkv, knn, ao, xw_sum, xw_cnt);

  // x_out = attn_o @ out_proj_w.T + x   [32768,256] f32
  gemm_bf16<false><<<dim3(NP/128, 256/128), 256, 0, stream>>>(ao, wb + 768*256, out, x, 256);

  finalize_xw<<<NP / 256, 256, 0, stream>>>(xw_sum, xw_cnt, out + (size_t)NP * EE);
}

// Round 8
// 362.365 us; speedup vs baseline: 2.4337x; 2.4337x over previous
//
#include <hip/hip_runtime.h>
#include <hip/hip_bf16.h>
#include <math.h>

// Problem constants
#define BB 4
#define VV 8192
#define EE 256
#define HH 8
#define KK 6
#define NP (BB*VV)          // 32768 points total

// ---------------- workspace layout (bytes), total ~86 MB ----------------
#define OFF_XV4 0            // float4[NP]            524288
#define OFF_KNN 524288       // int[NP*6]             786432
#define OFF_XWS 1310720      // float[NP]             131072
#define OFF_XWC 1441792      // float[NP]             131072
#define OFF_XB  1572864      // bf16[NP*256]          16777216
#define OFF_WB  18350080     // bf16[1024*256]        524288
#define OFF_QKV 18874368     // bf16[NP*768]          50331648
#define OFF_AO  69206016     // bf16[NP*256]          16777216 -> ends 85983232

typedef float f32x4 __attribute__((ext_vector_type(4)));
typedef __bf16 bf16x8 __attribute__((ext_vector_type(8)));

__device__ __forceinline__ unsigned short f2b(float f) {
  __hip_bfloat16 h = __float2bfloat16(f);
  return *reinterpret_cast<unsigned short*>(&h);
}
__device__ __forceinline__ float b2f(unsigned short u) {
  unsigned v = ((unsigned)u) << 16;
  return __uint_as_float(v);
}

// monotone float -> uint map (total order)
__device__ __forceinline__ unsigned sortable(float f) {
  unsigned u = __float_as_uint(f);
  return u ^ ((unsigned)((int)u >> 31) | 0x80000000u);
}
__device__ __forceinline__ unsigned long long pack_key(float dist, int j) {
  return ((unsigned long long)sortable(dist) << 32) | (unsigned)j;
}
__device__ __forceinline__ float unpack_dist(unsigned long long k) {
  unsigned du = (unsigned)(k >> 32);
  du = (du & 0x80000000u) ? (du ^ 0x80000000u) : ~du;
  return __uint_as_float(du);
}

// key for an empty slot: dist=+INF, idx=0xFFFFFFFF (any real key sorts below)
#define KINF 0xFF800000FFFFFFFFull

#define INSU(key) \
  if (key < k5) { \
    bool b4 = key < k4, b3 = key < k3, b2 = key < k2, b1 = key < k1, b0 = key < k0; \
    k5 = b4 ? k4 : key; \
    k4 = b4 ? (b3 ? k3 : key) : k4; \
    k3 = b3 ? (b2 ? k2 : key) : k3; \
    k2 = b2 ? (b1 ? k1 : key) : k2; \
    k1 = b1 ? (b0 ? k0 : key) : k1; \
    k0 = b0 ? key : k0; \
  }

// ---------------- prep: pack xyz+sq, zero scatter accumulators ----------------
__global__ void prep_kernel(const float* __restrict__ xv, float4* __restrict__ xv4,
                            float* __restrict__ xw_sum, float* __restrict__ xw_cnt) {
  int i = blockIdx.x * blockDim.x + threadIdx.x;
  if (i >= NP) return;
  float x0 = xv[i*3+0], x1 = xv[i*3+1], x2 = xv[i*3+2];
  // exact fp32 op order of the reference: ((x0*x0 + x1*x1) + x2*x2), no FMA contraction
  float sq = __fadd_rn(__fadd_rn(__fmul_rn(x0,x0), __fmul_rn(x1,x1)), __fmul_rn(x2,x2));
  xv4[i] = make_float4(x0, x1, x2, sq);
  xw_sum[i] = 0.f;
  xw_cnt[i] = 0.f;
}

// ---------------- f32 -> bf16 bulk convert (RNE) ----------------
__global__ void cvt_bf16(const float* __restrict__ src, unsigned short* __restrict__ dst, int n4) {
  int i = blockIdx.x * blockDim.x + threadIdx.x;
  if (i >= n4) return;
  float4 v = ((const float4*)src)[i];
  ushort4 o;
  o.x = f2b(v.x); o.y = f2b(v.y); o.z = f2b(v.z); o.w = f2b(v.w);
  ((ushort4*)dst)[i] = o;
}

// ---------------- brute-force KNN (r4 throughput structure, u64 insert) ----------------
// 32 queries/block x 8 chunk-waves (tid = c*32 + qb). Candidates staged in 16KB
// LDS tiles; each lane scans a 1024-candidate stream (j strictly increasing).
// Top-6 as packed u64 keys (sortable dist<<32 | idx): u64 order == lexicographic
// (dist, idx), lower index wins ties — exact jax.lax.top_k semantics. Fast-path
// gate is a float compare dist <= d5f; ties enter the body where the u64
// compare resolves them exactly.
__global__ __launch_bounds__(256) void knn_kernel(const float4* __restrict__ xv4,
                                                  int* __restrict__ knn_idx) {
  __shared__ float4 tile[1024];                    // 16 KB, reused for merge keys
  int tid = threadIdx.x;
  int qb = tid & 31;
  int c = tid >> 5;                                // chunk 0..7
  int q = blockIdx.x * 32 + qb;                    // global point id
  int base = (q >> 13) << 13;                      // batch base (8192 % 32 == 0)

  float4 me = xv4[q];
  float mx = me.x, my = me.y, mz = me.z, sqq = me.w;

  unsigned long long k0=KINF,k1=KINF,k2=KINF,k3=KINF,k4=KINF,k5=KINF;
  float d5f = INFINITY;

  for (int t = 0; t < 8; ++t) {
    __syncthreads();
#pragma unroll
    for (int u = 0; u < 4; ++u)
      tile[tid + u*256] = xv4[base + t*1024 + tid + u*256];
    __syncthreads();

    const float4* cp = &tile[c * 128];
    int jbase = t*1024 + c*128;
#pragma unroll 8
    for (int it = 0; it < 128; ++it) {
      float4 p = cp[it];
      // reference fp32 semantics: d = (sq_v + sq_w) - 2*dot, dot = ((x0*y0 + x1*y1) + x2*y2)
      float dot  = __fadd_rn(__fadd_rn(__fmul_rn(mx,p.x), __fmul_rn(my,p.y)), __fmul_rn(mz,p.z));
      float dist = __fsub_rn(__fadd_rn(sqq, p.w), __fmul_rn(2.0f, dot));
      if (dist <= d5f) {
        unsigned long long key = pack_key(dist, jbase + it);
        if (key < k5) {
          bool b4 = key < k4, b3 = key < k3, b2 = key < k2, b1 = key < k1, b0 = key < k0;
          k5 = b4 ? k4 : key;
          k4 = b4 ? (b3 ? k3 : key) : k4;
          k3 = b3 ? (b2 ? k2 : key) : k3;
          k2 = b2 ? (b1 ? k1 : key) : k2;
          k1 = b1 ? (b0 ? k0 : key) : k1;
          k0 = b0 ? key : k0;
          d5f = unpack_dist(k5);
        }
      }
    }
  }

  __syncthreads();   // tile reads done; safe to alias as merge buffer
  unsigned long long* mk = reinterpret_cast<unsigned long long*>(tile);  // mk[qb*43 + s]
  if (c > 0) {
    int o = qb*43 + (c-1)*6;
    mk[o+0]=k0; mk[o+1]=k1; mk[o+2]=k2;
    mk[o+3]=k3; mk[o+4]=k4; mk[o+5]=k5;
  }
  __syncthreads();
  if (c == 0) {
#pragma unroll
    for (int s = 0; s < 42; ++s) {
      unsigned long long key = mk[qb*43 + s];
      INSU(key);
    }
    knn_idx[q*6+0] = (int)(unsigned)k0;   // batch-local indices
    knn_idx[q*6+1] = (int)(unsigned)k1;
    knn_idx[q*6+2] = (int)(unsigned)k2;
    knn_idx[q*6+3] = (int)(unsigned)k3;
    knn_idx[q*6+4] = (int)(unsigned)k4;
    knn_idx[q*6+5] = (int)(unsigned)k5;
  }
}

// ---------------- bf16 MFMA GEMM: C[m,n] = sum_k A[m,k]*B[n,k], K=256 ----------------
template<bool OUT_BF16>
__global__ __launch_bounds__(256) void gemm_bf16(const unsigned short* __restrict__ A,
                                                 const unsigned short* __restrict__ Bw,
                                                 void* __restrict__ Cv,
                                                 const float* __restrict__ R,
                                                 int ldc) {
  __shared__ unsigned short ABs[8192];   // A tile [0,4096), B tile [4096,8192) ushort units
  int tid = threadIdx.x;
  int lane = tid & 63;
  int w = tid >> 6;
  int bm = blockIdx.x * 128;
  int bn = blockIdx.y * 128;
  int wr = w >> 1, wc = w & 1;

  f32x4 acc[4][4] = {};

  for (int ks = 0; ks < 8; ++ks) {
    int k0 = ks * 32;
    __syncthreads();
#pragma unroll
    for (int t = 0; t < 4; ++t) {
      int bg = (t*4 + w) * 64;           // wave-uniform granule base
      int g = bg + lane;
      const unsigned short* src;
      if (bg < 512) {                    // A granules
        int r = g >> 2, kb = g & 3;
        src = A + (size_t)(bm + r) * 256 + k0 + kb*8;
      } else {                           // B granules
        int g2 = g - 512;
        int r = g2 >> 2, kb = g2 & 3;
        src = Bw + (size_t)(bn + r) * 256 + k0 + kb*8;
      }
      __builtin_amdgcn_global_load_lds(
        (const __attribute__((address_space(1))) unsigned int*)src,
        (__attribute__((address_space(3))) unsigned int*)&ABs[bg*8],
        16, 0, 0);
    }
    __syncthreads();

    bf16x8 af[4], bfr[4];
#pragma unroll
    for (int m = 0; m < 4; ++m)
      af[m] = *(const bf16x8*)&ABs[(wr*64 + m*16 + (lane&15))*32 + (lane>>4)*8];
#pragma unroll
    for (int n = 0; n < 4; ++n)
      bfr[n] = *(const bf16x8*)&ABs[4096 + (wc*64 + n*16 + (lane&15))*32 + (lane>>4)*8];
#pragma unroll
    for (int m = 0; m < 4; ++m)
#pragma unroll
      for (int n = 0; n < 4; ++n)
        acc[m][n] = __builtin_amdgcn_mfma_f32_16x16x32_bf16(af[m], bfr[n], acc[m][n], 0, 0, 0);
  }

  int rb = bm + wr*64 + (lane>>4)*4;
  int cb = bn + wc*64 + (lane&15);
#pragma unroll
  for (int m = 0; m < 4; ++m)
#pragma unroll
    for (int n = 0; n < 4; ++n)
#pragma unroll
      for (int i = 0; i < 4; ++i) {
        int row = rb + m*16 + i;
        int col = cb + n*16;
        float v = acc[m][n][i];
        if (OUT_BF16) {
          ((unsigned short*)Cv)[(size_t)row*ldc + col] = f2b(v);
        } else {
          ((float*)Cv)[(size_t)row*ldc + col] = v + R[(size_t)row*ldc + col];
        }
      }
}

// ---------------- per-point attention: one wave per point (bf16 QKV) ----------------
__global__ __launch_bounds__(256) void attn_kernel(const unsigned short* __restrict__ QKV,
                                                   const int* __restrict__ knn_idx,
                                                   unsigned short* __restrict__ attn_out,
                                                   float* __restrict__ xw_sum,
                                                   float* __restrict__ xw_cnt) {
  int p = blockIdx.x * 4 + (threadIdx.x >> 6);   // point id
  int lane = threadIdx.x & 63;
  size_t gbase = (size_t)(p >> 13) << 13;        // batch base
  size_t prow = (size_t)p * 768;

  ushort4 qv = *(const ushort4*)&QKV[prow + lane*4];
  ushort4 sv = *(const ushort4*)&QKV[prow + 512 + lane*4];
  float qx=b2f(qv.x), qy=b2f(qv.y), qz=b2f(qv.z), qw=b2f(qv.w);
  float sx=b2f(sv.x), sy=b2f(sv.y), sz=b2f(sv.z), sw=b2f(sv.w);

  int idx[KK];
#pragma unroll
  for (int j = 0; j < KK; ++j) idx[j] = knn_idx[p*KK + j];

  float s[KK];
  float vx[KK], vy[KK], vz[KK], vw[KK];
#pragma unroll
  for (int j = 0; j < KK; ++j) {
    size_t r = (gbase + idx[j]) * 768;
    ushort4 kv = *(const ushort4*)&QKV[r + 256 + lane*4];
    ushort4 vv = *(const ushort4*)&QKV[r + 512 + lane*4];
    float t = qx*b2f(kv.x) + qy*b2f(kv.y) + qz*b2f(kv.z) + qw*b2f(kv.w);
    t += __shfl_xor(t, 1);
    t += __shfl_xor(t, 2);
    t += __shfl_xor(t, 4);
    s[j] = t * 0.17677669529663687f;   // 1/sqrt(32)
    vx[j] = b2f(vv.x); vy[j] = b2f(vv.y); vz[j] = b2f(vv.z); vw[j] = b2f(vv.w);
  }

  float m = s[0];
#pragma unroll
  for (int j = 1; j < KK; ++j) m = fmaxf(m, s[j]);
  float e[KK], denom = 0.f;
#pragma unroll
  for (int j = 0; j < KK; ++j) { e[j] = expf(s[j] - m); denom += e[j]; }
  float inv = 1.0f / denom;
#pragma unroll
  for (int j = 0; j < KK; ++j) e[j] *= inv;

  float ox=0.f, oy=0.f, oz=0.f, ow=0.f;
#pragma unroll
  for (int j = 0; j < KK; ++j) {
    float a = e[j];
    ox += a * (vx[j] - sx);
    oy += a * (vy[j] - sy);
    oz += a * (vz[j] - sz);
    ow += a * (vw[j] - sw);
  }
  ushort4 ov;
  ov.x = f2b(ox); ov.y = f2b(oy); ov.z = f2b(oz); ov.w = f2b(ow);
  *(ushort4*)&attn_out[(size_t)p * 256 + lane*4] = ov;

  // x_w scatter: mean over heads (orbit of xor{8,16,32} = one lane per head)
#pragma unroll
  for (int j = 0; j < KK; ++j) {
    float t = e[j];
    t += __shfl_xor(t, 8);
    t += __shfl_xor(t, 16);
    t += __shfl_xor(t, 32);
    if (lane == 0) {
      atomicAdd(&xw_sum[gbase + idx[j]], t * 0.125f);
      atomicAdd(&xw_cnt[gbase + idx[j]], 1.0f);
    }
  }
}

// ---------------- finalize: xw_out = sum/(count+1) ----------------
__global__ void finalize_xw(const float* __restrict__ xw_sum,
                            const float* __restrict__ xw_cnt,
                            float* __restrict__ out) {
  int i = blockIdx.x * blockDim.x + threadIdx.x;
  if (i < NP) out[i] = xw_sum[i] / (xw_cnt[i] + 1.0f);
}

extern "C" void kernel_launch(void* const* d_in, const int* in_sizes, int n_in,
                              void* d_out, int out_size, void* d_ws, size_t ws_size,
                              hipStream_t stream) {
  const float* x     = (const float*)d_in[0];   // [B,V,E]
  const float* xv    = (const float*)d_in[1];   // [B,V,3]
  const float* w_in  = (const float*)d_in[2];   // [3E,E]
  const float* w_out = (const float*)d_in[3];   // [E,E]
  float* out = (float*)d_out;

  char* ws = (char*)d_ws;
  float4*         xv4    = (float4*)(ws + OFF_XV4);
  int*            knn    = (int*)(ws + OFF_KNN);
  float*          xw_sum = (float*)(ws + OFF_XWS);
  float*          xw_cnt = (float*)(ws + OFF_XWC);
  unsigned short* xb     = (unsigned short*)(ws + OFF_XB);
  unsigned short* wb     = (unsigned short*)(ws + OFF_WB);
  unsigned short* qkv    = (unsigned short*)(ws + OFF_QKV);
  unsigned short* ao     = (unsigned short*)(ws + OFF_AO);

  prep_kernel<<<(NP + 255) / 256, 256, 0, stream>>>(xv, xv4, xw_sum, xw_cnt);
  cvt_bf16<<<(NP*256/4 + 255)/256, 256, 0, stream>>>(x, xb, NP*256/4);
  cvt_bf16<<<(768*256/4 + 255)/256, 256, 0, stream>>>(w_in, wb, 768*256/4);
  cvt_bf16<<<(256*256/4 + 255)/256, 256, 0, stream>>>(w_out, wb + 768*256, 256*256/4);

  knn_kernel<<<NP / 32, 256, 0, stream>>>(xv4, knn);

  // QKV = x @ in_proj_w.T   [32768,768] bf16
  gemm_bf16<true><<<dim3(NP/128, 768/128), 256, 0, stream>>>(xb, wb, qkv, nullptr, 768);

  attn_kernel<<<NP / 4, 256, 0, stream>>>(qkv, knn, ao, xw_sum, xw_cnt);

  // x_out = attn_o @ out_proj_w.T + x   [32768,256] f32
  gemm_bf16<false><<<dim3(NP/128, 256/128), 256, 0, stream>>>(ao, wb + 768*256, out, x, 256);

  finalize_xw<<<NP / 256, 256, 0, stream>>>(xw_sum, xw_cnt, out + (size_t)NP * EE);
}

// Round 9
// 297.110 us; speedup vs baseline: 2.9682x; 1.2196x over previous
//
#include <hip/hip_runtime.h>
#include <hip/hip_bf16.h>
#include <math.h>

// Problem constants
#define BB 4
#define VV 8192
#define EE 256
#define HH 8
#define KK 6
#define NP (BB*VV)          // 32768 points total

// ---------------- workspace layout (bytes), total ~86 MB ----------------
#define OFF_XV4 0            // float[NP*4] pair-SoA  524288
#define OFF_KNN 524288       // int[NP*6]             786432
#define OFF_XWS 1310720      // float[NP]             131072
#define OFF_XWC 1441792      // float[NP]             131072
#define OFF_XB  1572864      // bf16[NP*256]          16777216
#define OFF_WB  18350080     // bf16[1024*256]        524288
#define OFF_QKV 18874368     // bf16[NP*768]          50331648
#define OFF_AO  69206016     // bf16[NP*256]          16777216 -> ends 85983232

typedef float f32x4 __attribute__((ext_vector_type(4)));
typedef float f32x2 __attribute__((ext_vector_type(2)));
typedef __bf16 bf16x8 __attribute__((ext_vector_type(8)));

__device__ __forceinline__ unsigned short f2b(float f) {
  __hip_bfloat16 h = __float2bfloat16(f);
  return *reinterpret_cast<unsigned short*>(&h);
}
__device__ __forceinline__ float b2f(unsigned short u) {
  unsigned v = ((unsigned)u) << 16;
  return __uint_as_float(v);
}

// monotone float -> uint map (total order)
__device__ __forceinline__ unsigned sortable(float f) {
  unsigned u = __float_as_uint(f);
  return u ^ ((unsigned)((int)u >> 31) | 0x80000000u);
}
__device__ __forceinline__ unsigned long long pack_key(float dist, int j) {
  return ((unsigned long long)sortable(dist) << 32) | (unsigned)j;
}

// float dual-chain insert (r4-proven): precondition dist < d5.
// Strict < + strictly-increasing j per lane == exact (dist, idx) lexicographic.
#define INSERT6(dist,j) { \
  bool b4 = dist < d4, b3 = dist < d3, b2 = dist < d2, b1 = dist < d1, b0 = dist < d0; \
  d5 = b4 ? d4 : dist;             i5 = b4 ? i4 : j; \
  d4 = b4 ? (b3 ? d3 : dist) : d4; i4 = b4 ? (b3 ? i3 : j) : i4; \
  d3 = b3 ? (b2 ? d2 : dist) : d3; i3 = b3 ? (b2 ? i2 : j) : i3; \
  d2 = b2 ? (b1 ? d1 : dist) : d2; i2 = b2 ? (b1 ? i1 : j) : i2; \
  d1 = b1 ? (b0 ? d0 : dist) : d1; i1 = b1 ? (b0 ? i0 : j) : i1; \
  d0 = b0 ? dist : d0;             i0 = b0 ? j : i0; \
}

#define INSU(key) \
  if (key < k5) { \
    bool b4 = key < k4, b3 = key < k3, b2 = key < k2, b1 = key < k1, b0 = key < k0; \
    k5 = b4 ? k4 : key; \
    k4 = b4 ? (b3 ? k3 : key) : k4; \
    k3 = b3 ? (b2 ? k2 : key) : k3; \
    k2 = b2 ? (b1 ? k1 : key) : k2; \
    k1 = b1 ? (b0 ? k0 : key) : k1; \
    k0 = b0 ? key : k0; \
  }

// ---------------- prep: pack xyz+sq into PAIR-SoA, zero scatter accumulators --
// Pair p (candidates 2p,2p+1) occupies 8 floats: {x0,x1,y0,y1,z0,z1,w0,w1}.
__global__ void prep_kernel(const float* __restrict__ xv, float* __restrict__ xv4p,
                            float* __restrict__ xw_sum, float* __restrict__ xw_cnt) {
  int i = blockIdx.x * blockDim.x + threadIdx.x;
  if (i >= NP) return;
  float x0 = xv[i*3+0], x1 = xv[i*3+1], x2 = xv[i*3+2];
  // exact fp32 op order of the reference: ((x0*x0 + x1*x1) + x2*x2), no FMA contraction
  float sq = __fadd_rn(__fadd_rn(__fmul_rn(x0,x0), __fmul_rn(x1,x1)), __fmul_rn(x2,x2));
  float* blk = xv4p + (size_t)(i >> 1) * 8;
  int h = i & 1;
  blk[0 + h] = x0; blk[2 + h] = x1; blk[4 + h] = x2; blk[6 + h] = sq;
  xw_sum[i] = 0.f;
  xw_cnt[i] = 0.f;
}

// ---------------- f32 -> bf16 bulk convert (RNE) ----------------
__global__ void cvt_bf16(const float* __restrict__ src, unsigned short* __restrict__ dst, int n4) {
  int i = blockIdx.x * blockDim.x + threadIdx.x;
  if (i >= n4) return;
  float4 v = ((const float4*)src)[i];
  ushort4 o;
  o.x = f2b(v.x); o.y = f2b(v.y); o.z = f2b(v.z); o.w = f2b(v.w);
  ((ushort4*)dst)[i] = o;
}

// ---------------- fused front: KNN (VALU pipe) + GEMM1 (MFMA pipe) ----------------
// 2560 blocks, interleaved 2:3 so each CU hosts both kinds concurrently.
// KNN part (1024 blocks): r4 structure — 32 queries x 8 chunk-waves, 16KB LDS
// candidate tiles (pair-SoA), packed-f32 distance math, float dual-chain top-6,
// u64-key cross-chunk merge (exact jax.lax.top_k tie-break).
// GEMM part (1536 blocks): QKV = x @ in_proj_w.T, 128x128 tile, bf16 MFMA.
__global__ __launch_bounds__(256) void front_kernel(const float* __restrict__ xv4p,
                                                    int* __restrict__ knn_idx,
                                                    const unsigned short* __restrict__ A,
                                                    const unsigned short* __restrict__ Bw,
                                                    unsigned short* __restrict__ qkv) {
  __shared__ __align__(16) float ldsf[4096];   // 16 KB, shared by both paths
  int bid = blockIdx.x;
  int rsel = bid % 5;
  int tid = threadIdx.x;

  if (rsel < 2) {
    // ================= KNN path =================
#pragma clang fp contract(off)
    int kb = (bid / 5) * 2 + rsel;               // 0..1023
    float* tile = ldsf;
    int qb = tid & 31;
    int c = tid >> 5;                            // chunk 0..7
    int q = kb * 32 + qb;                        // global point id
    int base = (q >> 13) << 13;                  // batch base (8192 % 32 == 0)

    // query coords from pair-SoA block
    const f32x4* qblk = (const f32x4*)(xv4p + (size_t)(q >> 1) * 8);
    f32x4 qa = qblk[0], qc = qblk[1];
    int h = q & 1;
    float mx = qa[h], my = qa[2 + h], mz = qc[h], sqq = qc[2 + h];
    f32x2 mx2 = {mx, mx}, my2 = {my, my}, mz2 = {mz, mz}, sq2 = {sqq, sqq};

    float d0=INFINITY,d1=INFINITY,d2=INFINITY,d3=INFINITY,d4=INFINITY,d5=INFINITY;
    int   i0=0x7fffffff,i1=0x7fffffff,i2=0x7fffffff,i3=0x7fffffff,i4=0x7fffffff,i5=0x7fffffff;

    const f32x4* gsrc = (const f32x4*)xv4p;      // pair-SoA == contiguous float4 stream
    for (int t = 0; t < 8; ++t) {
      __syncthreads();
      f32x4* t4 = (f32x4*)tile;
#pragma unroll
      for (int u = 0; u < 4; ++u)
        t4[tid + u*256] = gsrc[base + t*1024 + tid + u*256];
      __syncthreads();

      const f32x4* tp = (const f32x4*)tile;
      int jbase = t*1024 + c*128;
#pragma unroll 8
      for (int it = 0; it < 64; ++it) {
        f32x4 a = tp[(c*64 + it)*2];
        f32x4 b = tp[(c*64 + it)*2 + 1];
        f32x2 px2 = __builtin_shufflevector(a, a, 0, 1);
        f32x2 py2 = __builtin_shufflevector(a, a, 2, 3);
        f32x2 pz2 = __builtin_shufflevector(b, b, 0, 1);
        f32x2 pw2 = __builtin_shufflevector(b, b, 2, 3);
        // reference fp32 semantics per element: d = (sq_v + sq_w) - 2*((xx+yy)+zz)
        // (contract(off); 2*dot is exact so final sub rounds identically)
        f32x2 dot2  = (mx2*px2 + my2*py2) + mz2*pz2;
        f32x2 dist2 = (sq2 + pw2) - 2.0f*dot2;
        float dl = dist2[0], dh = dist2[1];
        int j0 = jbase + 2*it;
        if (dl < d5) { INSERT6(dl, j0); }
        if (dh < d5) { int j1 = j0 + 1; INSERT6(dh, j1); }
      }
    }

    __syncthreads();   // tile reads done; safe to alias as merge buffer
    unsigned long long* mk = reinterpret_cast<unsigned long long*>(tile);  // mk[qb*43 + s]
    if (c > 0) {
      int o = qb*43 + (c-1)*6;
      mk[o+0]=pack_key(d0,i0); mk[o+1]=pack_key(d1,i1); mk[o+2]=pack_key(d2,i2);
      mk[o+3]=pack_key(d3,i3); mk[o+4]=pack_key(d4,i4); mk[o+5]=pack_key(d5,i5);
    }
    __syncthreads();
    if (c == 0) {
      unsigned long long k0=pack_key(d0,i0),k1=pack_key(d1,i1),k2=pack_key(d2,i2),
                         k3=pack_key(d3,i3),k4=pack_key(d4,i4),k5=pack_key(d5,i5);
      for (int s = 0; s < 42; ++s) {
        unsigned long long key = mk[qb*43 + s];
        INSU(key);
      }
      knn_idx[q*6+0] = (int)(unsigned)k0;   // batch-local indices
      knn_idx[q*6+1] = (int)(unsigned)k1;
      knn_idx[q*6+2] = (int)(unsigned)k2;
      knn_idx[q*6+3] = (int)(unsigned)k3;
      knn_idx[q*6+4] = (int)(unsigned)k4;
      knn_idx[q*6+5] = (int)(unsigned)k5;
    }
    return;
  }

  // ================= GEMM path: qkv = x @ in_proj_w.T =================
  int gb = (bid / 5) * 3 + (rsel - 2);           // 0..1535
  unsigned short* ABs = (unsigned short*)ldsf;   // A tile [0,4096), B tile [4096,8192)
  int lane = tid & 63;
  int w = tid >> 6;
  int bm = (gb % 256) * 128;
  int bn = (gb / 256) * 128;
  int wr = w >> 1, wc = w & 1;

  f32x4 acc[4][4] = {};

  for (int ks = 0; ks < 8; ++ks) {
    int k0 = ks * 32;
    __syncthreads();
#pragma unroll
    for (int t = 0; t < 4; ++t) {
      int bg = (t*4 + w) * 64;           // wave-uniform granule base
      int g = bg + lane;
      const unsigned short* src;
      if (bg < 512) {                    // A granules
        int r = g >> 2, kb2 = g & 3;
        src = A + (size_t)(bm + r) * 256 + k0 + kb2*8;
      } else {                           // B granules
        int g2 = g - 512;
        int r = g2 >> 2, kb2 = g2 & 3;
        src = Bw + (size_t)(bn + r) * 256 + k0 + kb2*8;
      }
      __builtin_amdgcn_global_load_lds(
        (const __attribute__((address_space(1))) unsigned int*)src,
        (__attribute__((address_space(3))) unsigned int*)&ABs[bg*8],
        16, 0, 0);
    }
    __syncthreads();

    bf16x8 af[4], bfr[4];
#pragma unroll
    for (int m = 0; m < 4; ++m)
      af[m] = *(const bf16x8*)&ABs[(wr*64 + m*16 + (lane&15))*32 + (lane>>4)*8];
#pragma unroll
    for (int n = 0; n < 4; ++n)
      bfr[n] = *(const bf16x8*)&ABs[4096 + (wc*64 + n*16 + (lane&15))*32 + (lane>>4)*8];
#pragma unroll
    for (int m = 0; m < 4; ++m)
#pragma unroll
      for (int n = 0; n < 4; ++n)
        acc[m][n] = __builtin_amdgcn_mfma_f32_16x16x32_bf16(af[m], bfr[n], acc[m][n], 0, 0, 0);
  }

  int rb = bm + wr*64 + (lane>>4)*4;
  int cb = bn + wc*64 + (lane&15);
#pragma unroll
  for (int m = 0; m < 4; ++m)
#pragma unroll
    for (int n = 0; n < 4; ++n)
#pragma unroll
      for (int i = 0; i < 4; ++i) {
        int row = rb + m*16 + i;
        int col = cb + n*16;
        qkv[(size_t)row*768 + col] = f2b(acc[m][n][i]);
      }
}

// ---------------- bf16 MFMA GEMM (standalone, f32-out + residual) ----------------
__global__ __launch_bounds__(256) void gemm_bf16_f32(const unsigned short* __restrict__ A,
                                                     const unsigned short* __restrict__ Bw,
                                                     float* __restrict__ C,
                                                     const float* __restrict__ R,
                                                     int ldc) {
  __shared__ unsigned short ABs[8192];
  int tid = threadIdx.x;
  int lane = tid & 63;
  int w = tid >> 6;
  int bm = blockIdx.x * 128;
  int bn = blockIdx.y * 128;
  int wr = w >> 1, wc = w & 1;

  f32x4 acc[4][4] = {};

  for (int ks = 0; ks < 8; ++ks) {
    int k0 = ks * 32;
    __syncthreads();
#pragma unroll
    for (int t = 0; t < 4; ++t) {
      int bg = (t*4 + w) * 64;
      int g = bg + lane;
      const unsigned short* src;
      if (bg < 512) {
        int r = g >> 2, kb2 = g & 3;
        src = A + (size_t)(bm + r) * 256 + k0 + kb2*8;
      } else {
        int g2 = g - 512;
        int r = g2 >> 2, kb2 = g2 & 3;
        src = Bw + (size_t)(bn + r) * 256 + k0 + kb2*8;
      }
      __builtin_amdgcn_global_load_lds(
        (const __attribute__((address_space(1))) unsigned int*)src,
        (__attribute__((address_space(3))) unsigned int*)&ABs[bg*8],
        16, 0, 0);
    }
    __syncthreads();

    bf16x8 af[4], bfr[4];
#pragma unroll
    for (int m = 0; m < 4; ++m)
      af[m] = *(const bf16x8*)&ABs[(wr*64 + m*16 + (lane&15))*32 + (lane>>4)*8];
#pragma unroll
    for (int n = 0; n < 4; ++n)
      bfr[n] = *(const bf16x8*)&ABs[4096 + (wc*64 + n*16 + (lane&15))*32 + (lane>>4)*8];
#pragma unroll
    for (int m = 0; m < 4; ++m)
#pragma unroll
      for (int n = 0; n < 4; ++n)
        acc[m][n] = __builtin_amdgcn_mfma_f32_16x16x32_bf16(af[m], bfr[n], acc[m][n], 0, 0, 0);
  }

  int rb = bm + wr*64 + (lane>>4)*4;
  int cb = bn + wc*64 + (lane&15);
#pragma unroll
  for (int m = 0; m < 4; ++m)
#pragma unroll
    for (int n = 0; n < 4; ++n)
#pragma unroll
      for (int i = 0; i < 4; ++i) {
        int row = rb + m*16 + i;
        int col = cb + n*16;
        C[(size_t)row*ldc + col] = acc[m][n][i] + R[(size_t)row*ldc + col];
      }
}

// ---------------- per-point attention: one wave per point (bf16 QKV) ----------------
__global__ __launch_bounds__(256) void attn_kernel(const unsigned short* __restrict__ QKV,
                                                   const int* __restrict__ knn_idx,
                                                   unsigned short* __restrict__ attn_out,
                                                   float* __restrict__ xw_sum,
                                                   float* __restrict__ xw_cnt) {
  int p = blockIdx.x * 4 + (threadIdx.x >> 6);   // point id
  int lane = threadIdx.x & 63;
  size_t gbase = (size_t)(p >> 13) << 13;        // batch base
  size_t prow = (size_t)p * 768;

  ushort4 qv = *(const ushort4*)&QKV[prow + lane*4];
  ushort4 sv = *(const ushort4*)&QKV[prow + 512 + lane*4];
  float qx=b2f(qv.x), qy=b2f(qv.y), qz=b2f(qv.z), qw=b2f(qv.w);
  float sx=b2f(sv.x), sy=b2f(sv.y), sz=b2f(sv.z), sw=b2f(sv.w);

  int idx[KK];
#pragma unroll
  for (int j = 0; j < KK; ++j) idx[j] = knn_idx[p*KK + j];

  float s[KK];
  float vx[KK], vy[KK], vz[KK], vw[KK];
#pragma unroll
  for (int j = 0; j < KK; ++j) {
    size_t r = (gbase + idx[j]) * 768;
    ushort4 kv = *(const ushort4*)&QKV[r + 256 + lane*4];
    ushort4 vv = *(const ushort4*)&QKV[r + 512 + lane*4];
    float t = qx*b2f(kv.x) + qy*b2f(kv.y) + qz*b2f(kv.z) + qw*b2f(kv.w);
    t += __shfl_xor(t, 1);
    t += __shfl_xor(t, 2);
    t += __shfl_xor(t, 4);
    s[j] = t * 0.17677669529663687f;   // 1/sqrt(32)
    vx[j] = b2f(vv.x); vy[j] = b2f(vv.y); vz[j] = b2f(vv.z); vw[j] = b2f(vv.w);
  }

  float m = s[0];
#pragma unroll
  for (int j = 1; j < KK; ++j) m = fmaxf(m, s[j]);
  float e[KK], denom = 0.f;
#pragma unroll
  for (int j = 0; j < KK; ++j) { e[j] = expf(s[j] - m); denom += e[j]; }
  float inv = 1.0f / denom;
#pragma unroll
  for (int j = 0; j < KK; ++j) e[j] *= inv;

  float ox=0.f, oy=0.f, oz=0.f, ow=0.f;
#pragma unroll
  for (int j = 0; j < KK; ++j) {
    float a = e[j];
    ox += a * (vx[j] - sx);
    oy += a * (vy[j] - sy);
    oz += a * (vz[j] - sz);
    ow += a * (vw[j] - sw);
  }
  ushort4 ov;
  ov.x = f2b(ox); ov.y = f2b(oy); ov.z = f2b(oz); ov.w = f2b(ow);
  *(ushort4*)&attn_out[(size_t)p * 256 + lane*4] = ov;

  // x_w scatter: mean over heads (orbit of xor{8,16,32} = one lane per head)
#pragma unroll
  for (int j = 0; j < KK; ++j) {
    float t = e[j];
    t += __shfl_xor(t, 8);
    t += __shfl_xor(t, 16);
    t += __shfl_xor(t, 32);
    if (lane == 0) {
      atomicAdd(&xw_sum[gbase + idx[j]], t * 0.125f);
      atomicAdd(&xw_cnt[gbase + idx[j]], 1.0f);
    }
  }
}

// ---------------- finalize: xw_out = sum/(count+1) ----------------
__global__ void finalize_xw(const float* __restrict__ xw_sum,
                            const float* __restrict__ xw_cnt,
                            float* __restrict__ out) {
  int i = blockIdx.x * blockDim.x + threadIdx.x;
  if (i < NP) out[i] = xw_sum[i] / (xw_cnt[i] + 1.0f);
}

extern "C" void kernel_launch(void* const* d_in, const int* in_sizes, int n_in,
                              void* d_out, int out_size, void* d_ws, size_t ws_size,
                              hipStream_t stream) {
  const float* x     = (const float*)d_in[0];   // [B,V,E]
  const float* xv    = (const float*)d_in[1];   // [B,V,3]
  const float* w_in  = (const float*)d_in[2];   // [3E,E]
  const float* w_out = (const float*)d_in[3];   // [E,E]
  float* out = (float*)d_out;

  char* ws = (char*)d_ws;
  float*          xv4p   = (float*)(ws + OFF_XV4);
  int*            knn    = (int*)(ws + OFF_KNN);
  float*          xw_sum = (float*)(ws + OFF_XWS);
  float*          xw_cnt = (float*)(ws + OFF_XWC);
  unsigned short* xb     = (unsigned short*)(ws + OFF_XB);
  unsigned short* wb     = (unsigned short*)(ws + OFF_WB);
  unsigned short* qkv    = (unsigned short*)(ws + OFF_QKV);
  unsigned short* ao     = (unsigned short*)(ws + OFF_AO);

  prep_kernel<<<(NP + 255) / 256, 256, 0, stream>>>(xv, xv4p, xw_sum, xw_cnt);
  cvt_bf16<<<(NP*256/4 + 255)/256, 256, 0, stream>>>(x, xb, NP*256/4);
  cvt_bf16<<<(768*256/4 + 255)/256, 256, 0, stream>>>(w_in, wb, 768*256/4);
  cvt_bf16<<<(256*256/4 + 255)/256, 256, 0, stream>>>(w_out, wb + 768*256, 256*256/4);

  // fused: KNN (1024 virtual blocks) + QKV GEMM (1536 virtual blocks), 2:3 interleave
  front_kernel<<<2560, 256, 0, stream>>>(xv4p, knn, xb, wb, qkv);

  attn_kernel<<<NP / 4, 256, 0, stream>>>(qkv, knn, ao, xw_sum, xw_cnt);

  // x_out = attn_o @ out_proj_w.T + x   [32768,256] f32
  gemm_bf16_f32<<<dim3(NP/128, 256/128), 256, 0, stream>>>(ao, wb + 768*256, out, x, 256);

  finalize_xw<<<NP / 256, 256, 0, stream>>>(xw_sum, xw_cnt, out + (size_t)NP * EE);
}